// Round 1
// baseline (735.503 us; speedup 1.0000x reference)
//
#include <hip/hip_runtime.h>

// Playlist model: 15 embedding gathers -> concat [B,1920] -> low-rank cross ->
// MLP 1920->512->256->128 -> L2 normalize.  fp32 baseline, tiled GEMMs.

constexpr int B_ = 8192;
constexpr int D_ = 128;
constexpr int L_ = 5;
constexpr int F_ = 1920;   // 15 * 128
constexpr int P_ = 100;

struct GatherArgs {
  const int*   idx[15];
  const float* tab[15];
};

// One block per batch row; 128 threads = one per embedding dim.
__global__ __launch_bounds__(128)
void gather_pool_kernel(GatherArgs ga, float* __restrict__ X) {
  const int b = blockIdx.x;
  const int d = threadIdx.x;
  float* xr = X + (size_t)b * F_;
  // slots 0..5: single-index gathers
#pragma unroll
  for (int s = 0; s < 6; ++s) {
    const int i = ga.idx[s][b];
    xr[s * D_ + d] = ga.tab[s][(size_t)i * D_ + d];
  }
  // slots 6..14: pooled over L=5.  6..10 and 14 are masked-mean (idx!=0),
  // 11..13 are plain mean over 5.
#pragma unroll
  for (int s = 6; s < 15; ++s) {
    const bool masked = (s < 11) || (s == 14);
    const int* ip = ga.idx[s] + b * L_;
    float sum = 0.f, cnt = 0.f;
#pragma unroll
    for (int l = 0; l < L_; ++l) {
      const int i = ip[l];
      const float e = ga.tab[s][(size_t)i * D_ + d];
      if (!masked || i != 0) { sum += e; cnt += 1.f; }
    }
    const float denom = masked ? fmaxf(cnt, 1.f) : (float)L_;
    xr[s * D_ + d] = sum / denom;
  }
}

// Tiled fp32 GEMM: C[M,N] = A[M,K] @ B[K,N] (+epilogue).
// EPI: 0 = (+bias if non-null), 1 = bias+ReLU, 2 = cross: x*(acc+b)+x.
// BM=128, BN=64, BK=16, 256 threads, 8x4 per-thread micro-tile.
template<int EPI>
__global__ __launch_bounds__(256)
void gemm128x64(const float* __restrict__ A, const float* __restrict__ Bm,
                const float* __restrict__ bias, const float* __restrict__ X0,
                float* __restrict__ C, int M, int N, int K)
{
  constexpr int BM = 128, BN = 64, BK = 16, TM = 8, TN = 4;
  __shared__ float As[BK][BM];   // transposed: As[k][m]
  __shared__ float Bs[BK][BN];   // Bs[k][n]
  const int tid  = threadIdx.x;
  const int tx   = tid & 15;     // col group (0..15) -> 4 cols
  const int ty   = tid >> 4;     // row group (0..15) -> 8 rows
  const int row0 = blockIdx.y * BM;
  const int n0   = blockIdx.x * BN;

  float acc[TM][TN] = {};

  const int a_c = (tid & 3) * 4;        // k-offset of this thread's A float4
  const int b_k = tid >> 4;             // k-row of this thread's B float4
  const int b_n = (tid & 15) * 4;       // n-offset

  for (int k0 = 0; k0 < K; k0 += BK) {
    const bool fullK = (k0 + BK <= K);
    // ---- stage A tile (128x16) ----
#pragma unroll
    for (int it = 0; it < 2; ++it) {
      const int a_r = (tid >> 2) + it * 64;
      const float* ap = A + (size_t)(row0 + a_r) * K + k0 + a_c;
      float4 av;
      if (fullK) {
        av = *(const float4*)ap;
      } else {
        av.x = (k0 + a_c + 0 < K) ? ap[0] : 0.f;
        av.y = (k0 + a_c + 1 < K) ? ap[1] : 0.f;
        av.z = (k0 + a_c + 2 < K) ? ap[2] : 0.f;
        av.w = (k0 + a_c + 3 < K) ? ap[3] : 0.f;
      }
      As[a_c + 0][a_r] = av.x;
      As[a_c + 1][a_r] = av.y;
      As[a_c + 2][a_r] = av.z;
      As[a_c + 3][a_r] = av.w;
    }
    // ---- stage B tile (16x64) ----
    {
      const bool kin = (k0 + b_k) < K;
      const float* bp = Bm + (size_t)(k0 + b_k) * N + n0 + b_n;
      float4 bv;
      if (kin && (n0 + BN <= N)) {
        bv = *(const float4*)bp;
      } else {
        bv.x = (kin && n0 + b_n + 0 < N) ? bp[0] : 0.f;
        bv.y = (kin && n0 + b_n + 1 < N) ? bp[1] : 0.f;
        bv.z = (kin && n0 + b_n + 2 < N) ? bp[2] : 0.f;
        bv.w = (kin && n0 + b_n + 3 < N) ? bp[3] : 0.f;
      }
      *(float4*)&Bs[b_k][b_n] = bv;
    }
    __syncthreads();
    // ---- compute ----
#pragma unroll
    for (int kk = 0; kk < BK; ++kk) {
      float a[TM], bb[TN];
#pragma unroll
      for (int i = 0; i < TM; ++i) a[i] = As[kk][ty * TM + i];
#pragma unroll
      for (int j = 0; j < TN; ++j) bb[j] = Bs[kk][tx * TN + j];
#pragma unroll
      for (int i = 0; i < TM; ++i)
#pragma unroll
        for (int j = 0; j < TN; ++j)
          acc[i][j] = fmaf(a[i], bb[j], acc[i][j]);
    }
    __syncthreads();
  }
  // ---- epilogue + store ----
#pragma unroll
  for (int i = 0; i < TM; ++i) {
    const int m = row0 + ty * TM + i;
#pragma unroll
    for (int j = 0; j < TN; ++j) {
      const int n = n0 + tx * TN + j;
      if (n < N) {
        float v = acc[i][j];
        if (EPI == 0) {
          if (bias) v += bias[n];
        } else if (EPI == 1) {
          v = fmaxf(v + bias[n], 0.f);
        } else {
          const float x = X0[(size_t)m * N + n];
          v = fmaf(x, v + bias[n], x);
        }
        C[(size_t)m * N + n] = v;
      }
    }
  }
}

// L2 normalize rows of H [B,128] -> out.  One wave per row.
__global__ __launch_bounds__(256)
void l2norm_kernel(const float* __restrict__ H, float* __restrict__ out) {
  const int w    = threadIdx.x >> 6;
  const int lane = threadIdx.x & 63;
  const int b    = blockIdx.x * 4 + w;
  const float* hr = H + (size_t)b * 128;
  const float v0 = hr[lane];
  const float v1 = hr[lane + 64];
  float s = v0 * v0 + v1 * v1;
#pragma unroll
  for (int off = 32; off; off >>= 1) s += __shfl_xor(s, off);
  const float r = rsqrtf(fmaxf(s, 1e-12f));
  out[(size_t)b * 128 + lane]      = v0 * r;
  out[(size_t)b * 128 + lane + 64] = v1 * r;
}

extern "C" void kernel_launch(void* const* d_in, const int* in_sizes, int n_in,
                              void* d_out, int out_size, void* d_ws, size_t ws_size,
                              hipStream_t stream)
{
  GatherArgs ga;
  for (int s = 0; s < 15; ++s) {
    ga.idx[s] = (const int*)d_in[s];
    ga.tab[s] = (const float*)d_in[15 + s];
  }
  const float* cross_V = (const float*)d_in[30];  // [1920,100]
  const float* cross_U = (const float*)d_in[31];  // [100,1920]
  const float* cross_b = (const float*)d_in[32];  // [1920]
  const float* W0 = (const float*)d_in[33];       // [1920,512]
  const float* b0 = (const float*)d_in[34];
  const float* W1 = (const float*)d_in[35];       // [512,256]
  const float* b1 = (const float*)d_in[36];
  const float* W2 = (const float*)d_in[37];       // [256,128]
  const float* b2 = (const float*)d_in[38];

  float* ws = (float*)d_ws;
  float* X  = ws;                          // [B,1920]
  float* t  = X  + (size_t)B_ * F_;        // [B,100]
  float* h0 = t  + (size_t)B_ * P_;        // [B,512]
  float* h1 = h0 + (size_t)B_ * 512;       // [B,256]
  float* h2 = h1 + (size_t)B_ * 256;       // [B,128]

  // 1) gather + pool -> X
  gather_pool_kernel<<<B_, 128, 0, stream>>>(ga, X);
  // 2) t = X @ V                       [8192,100]
  gemm128x64<0><<<dim3(2, B_ / 128), 256, 0, stream>>>(
      X, cross_V, nullptr, nullptr, t, B_, P_, F_);
  // 3) X = X * (t @ U + b) + X  (in place)   [8192,1920]
  gemm128x64<2><<<dim3(F_ / 64, B_ / 128), 256, 0, stream>>>(
      t, cross_U, cross_b, X, X, B_, F_, P_);
  // 4) h0 = relu(X @ W0 + b0)          [8192,512]
  gemm128x64<1><<<dim3(512 / 64, B_ / 128), 256, 0, stream>>>(
      X, W0, b0, nullptr, h0, B_, 512, F_);
  // 5) h1 = relu(h0 @ W1 + b1)         [8192,256]
  gemm128x64<1><<<dim3(256 / 64, B_ / 128), 256, 0, stream>>>(
      h0, W1, b1, nullptr, h1, B_, 256, 512);
  // 6) h2 = h1 @ W2 + b2               [8192,128]
  gemm128x64<0><<<dim3(128 / 64, B_ / 128), 256, 0, stream>>>(
      h1, W2, b2, nullptr, h2, B_, 128, 256);
  // 7) L2 normalize -> out
  l2norm_kernel<<<B_ / 4, 256, 0, stream>>>(h2, (float*)d_out);
}

// Round 2
// 205.124 us; speedup vs baseline: 3.5856x; 3.5856x over previous
//
#include <hip/hip_runtime.h>

// Playlist model: gathers -> concat [B,1920] -> low-rank cross -> MLP -> L2 norm.
// bf16 MFMA GEMMs (16x16x32), fp32 accumulate, fused epilogues.

constexpr int B_ = 8192;
constexpr int D_ = 128;
constexpr int L_ = 5;
constexpr int F_ = 1920;   // 15 * 128
constexpr int P_ = 100;    // cross rank (padded to 128)

typedef __attribute__((ext_vector_type(8))) short short8;
typedef __attribute__((ext_vector_type(4))) float f32x4;

__device__ __forceinline__ unsigned short f2bf(float x) {
  union { float f; unsigned int u; } v; v.f = x;
  unsigned int r = v.u + 0x7FFF + ((v.u >> 16) & 1);   // RNE
  return (unsigned short)(r >> 16);
}
__device__ __forceinline__ float bf2f(unsigned short b) {
  union { unsigned int u; float f; } v; v.u = ((unsigned int)b) << 16;
  return v.f;
}

__device__ __forceinline__ void gload_lds16(const void* g, void* l) {
  __builtin_amdgcn_global_load_lds(
      (const __attribute__((address_space(1))) void*)g,
      (__attribute__((address_space(3))) void*)l, 16, 0, 0);
}

// ---------------- gather + pool -> X (bf16 [B,1920]) ----------------
struct GatherArgs {
  const int*   idx[15];
  const float* tab[15];
};

__global__ __launch_bounds__(128)
void gather_pool_kernel(GatherArgs ga, unsigned short* __restrict__ X) {
  const int b = blockIdx.x;
  const int d = threadIdx.x;
  unsigned short* xr = X + (size_t)b * F_;
#pragma unroll
  for (int s = 0; s < 6; ++s) {
    const int i = ga.idx[s][b];
    xr[s * D_ + d] = f2bf(ga.tab[s][(size_t)i * D_ + d]);
  }
#pragma unroll
  for (int s = 6; s < 15; ++s) {
    const bool masked = (s < 11) || (s == 14);   // 11..13 plain mean
    const int* ip = ga.idx[s] + b * L_;
    float sum = 0.f, cnt = 0.f;
#pragma unroll
    for (int l = 0; l < L_; ++l) {
      const int i = ip[l];
      const float e = ga.tab[s][(size_t)i * D_ + d];
      if (!masked || i != 0) { sum += e; cnt += 1.f; }
    }
    const float denom = masked ? fmaxf(cnt, 1.f) : (float)L_;
    xr[s * D_ + d] = f2bf(sum / denom);
  }
}

// ------------- transpose + pad fp32 -> bf16:  dst[c][r] = src[r][c] -------------
// src [R][C] fp32 row-major; dst [Cpad][Rpad] bf16; zero-filled outside (R,C).
__global__ __launch_bounds__(256)
void transpose_pad(const float* __restrict__ src, unsigned short* __restrict__ dst,
                   int R, int C, int Cpad, int Rpad)
{
  __shared__ float tile[32][33];
  const int r0 = blockIdx.x * 32, c0 = blockIdx.y * 32;
  const int tx = threadIdx.x & 31, ty = threadIdx.x >> 5;  // 32 x 8
#pragma unroll
  for (int i = 0; i < 32; i += 8) {
    const int r = r0 + ty + i, c = c0 + tx;
    tile[ty + i][tx] = (r < R && c < C) ? src[(size_t)r * C + c] : 0.f;
  }
  __syncthreads();
#pragma unroll
  for (int i = 0; i < 32; i += 8) {
    const int c = c0 + ty + i, r = r0 + tx;
    if (c < Cpad && r < Rpad)
      dst[(size_t)c * Rpad + r] = f2bf(tile[tx][ty + i]);
  }
}

// ---------------- bf16 MFMA GEMM: C[M,N] = A[M,K] @ Bt[N,K]^T ----------------
// 128x128 tile, BK=64, 4 waves (2x2, each 64x64 = 4x4 frags of 16x16x32).
// EPI: 0 = +bias -> fp32 | 1 = +bias,ReLU -> bf16 | 2 = pad-store -> bf16 (col<Nvalid else 0)
//      3 = cross: x*(acc+bias)+x -> bf16 in place (Cb is both input x and output)
template<int EPI>
__global__ __launch_bounds__(256)
void mfma_gemm(const unsigned short* __restrict__ A, const unsigned short* __restrict__ Bt,
               const float* __restrict__ bias, float* __restrict__ Cf,
               unsigned short* __restrict__ Cb, int M, int N, int K, int Nvalid)
{
  constexpr int BK = 64;
  __shared__ __align__(16) unsigned short As[128 * BK];
  __shared__ __align__(16) unsigned short Bs[128 * BK];
  const int tid  = threadIdx.x;
  const int wave = tid >> 6, lane = tid & 63;
  const int row0 = blockIdx.y * 128;
  const int n0   = blockIdx.x * 128;
  const int wr = (wave >> 1) * 64, wc = (wave & 1) * 64;
  // staging: slot s covers rows 8s..8s+7; lane -> row 8s+(lane>>3), lds chunk lane&7,
  // global chunk pre-swizzled so that LDS[r][cs] holds global chunk cs^(r&7).
  const int srow = lane >> 3;
  const int gc   = (lane & 7) ^ srow;

  f32x4 acc[4][4];
#pragma unroll
  for (int m = 0; m < 4; ++m)
#pragma unroll
    for (int n = 0; n < 4; ++n)
      acc[m][n] = (f32x4){0.f, 0.f, 0.f, 0.f};

  const size_t abase = (size_t)(row0 + srow) * K + (size_t)gc * 8;
  const size_t bbase = (size_t)(n0   + srow) * K + (size_t)gc * 8;

  for (int k0 = 0; k0 < K; k0 += BK) {
#pragma unroll
    for (int i = 0; i < 4; ++i) {
      const int s = wave * 4 + i;
      gload_lds16(A  + abase + (size_t)s * 8 * K + k0, As + s * 512);
      gload_lds16(Bt + bbase + (size_t)s * 8 * K + k0, Bs + s * 512);
    }
    __syncthreads();
#pragma unroll
    for (int ks = 0; ks < 2; ++ks) {
      short8 af[4], bfr[4];
#pragma unroll
      for (int m = 0; m < 4; ++m) {
        const int r  = wr + m * 16 + (lane & 15);
        const int cs = (ks * 4 + (lane >> 4)) ^ (r & 7);
        af[m] = *(const short8*)(As + r * 64 + cs * 8);
      }
#pragma unroll
      for (int n = 0; n < 4; ++n) {
        const int r  = wc + n * 16 + (lane & 15);
        const int cs = (ks * 4 + (lane >> 4)) ^ (r & 7);
        bfr[n] = *(const short8*)(Bs + r * 64 + cs * 8);
      }
#pragma unroll
      for (int m = 0; m < 4; ++m)
#pragma unroll
        for (int n = 0; n < 4; ++n)
          acc[m][n] = __builtin_amdgcn_mfma_f32_16x16x32_bf16(af[m], bfr[n], acc[m][n], 0, 0, 0);
    }
    __syncthreads();
  }

  const int l15 = lane & 15, l4 = lane >> 4;
#pragma unroll
  for (int m = 0; m < 4; ++m) {
#pragma unroll
    for (int n = 0; n < 4; ++n) {
      const int col = n0 + wc + n * 16 + l15;
      const float bv = (EPI == 2) ? 0.f : bias[col];
#pragma unroll
      for (int r = 0; r < 4; ++r) {
        const int row = row0 + wr + m * 16 + l4 * 4 + r;
        const float v = acc[m][n][r];
        if (EPI == 0) {
          Cf[(size_t)row * N + col] = v + bv;
        } else if (EPI == 1) {
          Cb[(size_t)row * N + col] = f2bf(fmaxf(v + bv, 0.f));
        } else if (EPI == 2) {
          Cb[(size_t)row * N + col] = (col < Nvalid) ? f2bf(v) : (unsigned short)0;
        } else {
          const float x = bf2f(Cb[(size_t)row * N + col]);
          Cb[(size_t)row * N + col] = f2bf(fmaf(x, v + bv, x));
        }
      }
    }
  }
}

// ---------------- L2 normalize rows of H [B,128] -> out fp32 ----------------
__global__ __launch_bounds__(256)
void l2norm_kernel(const float* __restrict__ H, float* __restrict__ out) {
  const int w    = threadIdx.x >> 6;
  const int lane = threadIdx.x & 63;
  const int b    = blockIdx.x * 4 + w;
  const float* hr = H + (size_t)b * 128;
  const float v0 = hr[lane];
  const float v1 = hr[lane + 64];
  float s = v0 * v0 + v1 * v1;
#pragma unroll
  for (int off = 32; off; off >>= 1) s += __shfl_xor(s, off);
  const float r = rsqrtf(fmaxf(s, 1e-12f));
  out[(size_t)b * 128 + lane]      = v0 * r;
  out[(size_t)b * 128 + lane + 64] = v1 * r;
}

extern "C" void kernel_launch(void* const* d_in, const int* in_sizes, int n_in,
                              void* d_out, int out_size, void* d_ws, size_t ws_size,
                              hipStream_t stream)
{
  GatherArgs ga;
  for (int s = 0; s < 15; ++s) {
    ga.idx[s] = (const int*)d_in[s];
    ga.tab[s] = (const float*)d_in[15 + s];
  }
  const float* cross_V = (const float*)d_in[30];  // [1920,100]
  const float* cross_U = (const float*)d_in[31];  // [100,1920]
  const float* cross_b = (const float*)d_in[32];  // [1920]
  const float* W0 = (const float*)d_in[33];       // [1920,512]
  const float* b0 = (const float*)d_in[34];
  const float* W1 = (const float*)d_in[35];       // [512,256]
  const float* b1 = (const float*)d_in[36];
  const float* W2 = (const float*)d_in[37];       // [256,128]
  const float* b2 = (const float*)d_in[38];

  char* w = (char*)d_ws;
  unsigned short* Xb  = (unsigned short*)w; w += (size_t)B_ * F_ * 2;    // [8192,1920] bf16
  unsigned short* t   = (unsigned short*)w; w += (size_t)B_ * 128 * 2;   // [8192,128] bf16 (pad 100->128)
  unsigned short* h0  = (unsigned short*)w; w += (size_t)B_ * 512 * 2;   // [8192,512] bf16
  unsigned short* h1  = (unsigned short*)w; w += (size_t)B_ * 256 * 2;   // [8192,256] bf16
  float*          h2  = (float*)w;          w += (size_t)B_ * 128 * 4;   // [8192,128] fp32
  unsigned short* Vt  = (unsigned short*)w; w += (size_t)128 * F_ * 2;   // [128,1920]
  unsigned short* Ut  = (unsigned short*)w; w += (size_t)F_ * 128 * 2;   // [1920,128]
  unsigned short* Wt0 = (unsigned short*)w; w += (size_t)512 * F_ * 2;   // [512,1920]
  unsigned short* Wt1 = (unsigned short*)w; w += (size_t)256 * 512 * 2;  // [256,512]
  unsigned short* Wt2 = (unsigned short*)w; w += (size_t)128 * 256 * 2;  // [128,256]

  const dim3 tb(256);
  // weight transposes (fp32 -> bf16, K-major, zero-padded)
  transpose_pad<<<dim3(F_ / 32, 128 / 32), tb, 0, stream>>>(cross_V, Vt, F_, P_, 128, F_);
  transpose_pad<<<dim3(128 / 32, F_ / 32), tb, 0, stream>>>(cross_U, Ut, P_, F_, F_, 128);
  transpose_pad<<<dim3(F_ / 32, 512 / 32), tb, 0, stream>>>(W0, Wt0, F_, 512, 512, F_);
  transpose_pad<<<dim3(512 / 32, 256 / 32), tb, 0, stream>>>(W1, Wt1, 512, 256, 256, 512);
  transpose_pad<<<dim3(256 / 32, 128 / 32), tb, 0, stream>>>(W2, Wt2, 256, 128, 128, 256);

  // 1) gather + pool -> Xb
  gather_pool_kernel<<<B_, 128, 0, stream>>>(ga, Xb);
  // 2) t = Xb @ V            [8192,128(100 valid)]
  mfma_gemm<2><<<dim3(1, B_ / 128), tb, 0, stream>>>(Xb, Vt, nullptr, nullptr, t,
                                                     B_, 128, F_, P_);
  // 3) Xb = x*(t @ U + b)+x  [8192,1920] in place
  mfma_gemm<3><<<dim3(F_ / 128, B_ / 128), tb, 0, stream>>>(t, Ut, cross_b, nullptr, Xb,
                                                            B_, F_, 128, F_);
  // 4) h0 = relu(Xb @ W0 + b0)   [8192,512]
  mfma_gemm<1><<<dim3(512 / 128, B_ / 128), tb, 0, stream>>>(Xb, Wt0, b0, nullptr, h0,
                                                             B_, 512, F_, 512);
  // 5) h1 = relu(h0 @ W1 + b1)   [8192,256]
  mfma_gemm<1><<<dim3(256 / 128, B_ / 128), tb, 0, stream>>>(h0, Wt1, b1, nullptr, h1,
                                                             B_, 256, 512, 256);
  // 6) h2 = h1 @ W2 + b2         [8192,128] fp32
  mfma_gemm<0><<<dim3(128 / 128, B_ / 128), tb, 0, stream>>>(h1, Wt2, b2, h2, nullptr,
                                                             B_, 128, 256, 128);
  // 7) L2 normalize -> out
  l2norm_kernel<<<B_ / 4, tb, 0, stream>>>(h2, (float*)d_out);
}

// Round 3
// 143.990 us; speedup vs baseline: 5.1080x; 1.4246x over previous
//
#include <hip/hip_runtime.h>

// Playlist model: gathers -> concat [B,1920] -> low-rank cross -> MLP -> L2 norm.
// bf16 MFMA GEMMs (16x16x32), fp32 accumulate, fused epilogues, shape-tuned tiles.

constexpr int B_ = 8192;
constexpr int D_ = 128;
constexpr int L_ = 5;
constexpr int F_ = 1920;   // 15 * 128
constexpr int P_ = 100;    // cross rank (padded to 128)

typedef __attribute__((ext_vector_type(8))) short short8;
typedef __attribute__((ext_vector_type(4))) float f32x4;
typedef __attribute__((ext_vector_type(4))) unsigned short u16x4;

__device__ __forceinline__ unsigned short f2bf(float x) {
  union { float f; unsigned int u; } v; v.f = x;
  unsigned int r = v.u + 0x7FFF + ((v.u >> 16) & 1);   // RNE
  return (unsigned short)(r >> 16);
}
__device__ __forceinline__ float bf2f(unsigned short b) {
  union { unsigned int u; float f; } v; v.u = ((unsigned int)b) << 16;
  return v.f;
}

__device__ __forceinline__ void gload_lds16(const void* g, void* l) {
  __builtin_amdgcn_global_load_lds(
      (const __attribute__((address_space(1))) void*)g,
      (__attribute__((address_space(3))) void*)l, 16, 0, 0);
}

// ---------------- gather + pool -> X (bf16 [B,1920]) ----------------
// 128 threads = 4 batch rows x 32 lanes; each lane reads one float4 chunk.
struct GatherArgs {
  const int*   idx[15];
  const float* tab[15];
};

__global__ __launch_bounds__(128)
void gather_pool_kernel(GatherArgs ga, unsigned short* __restrict__ X) {
  const int g = threadIdx.x >> 5;          // row group 0..3
  const int c = threadIdx.x & 31;          // float4 chunk 0..31
  const int b = blockIdx.x * 4 + g;
  unsigned short* xr = X + (size_t)b * F_;
#pragma unroll
  for (int s = 0; s < 6; ++s) {
    const int i = ga.idx[s][b];
    const float4 e = ((const float4*)(ga.tab[s] + (size_t)i * D_))[c];
    u16x4 o; o[0] = f2bf(e.x); o[1] = f2bf(e.y); o[2] = f2bf(e.z); o[3] = f2bf(e.w);
    *(u16x4*)(xr + s * D_ + c * 4) = o;
  }
#pragma unroll
  for (int s = 6; s < 15; ++s) {
    const bool masked = (s < 11) || (s == 14);   // 11..13 plain mean
    const int* ip = ga.idx[s] + b * L_;
    float sx = 0.f, sy = 0.f, sz = 0.f, sw = 0.f, cnt = 0.f;
#pragma unroll
    for (int l = 0; l < L_; ++l) {
      const int i = ip[l];
      const float4 e = ((const float4*)(ga.tab[s] + (size_t)i * D_))[c];
      if (!masked || i != 0) { sx += e.x; sy += e.y; sz += e.z; sw += e.w; cnt += 1.f; }
    }
    const float inv = 1.f / (masked ? fmaxf(cnt, 1.f) : (float)L_);
    u16x4 o; o[0] = f2bf(sx * inv); o[1] = f2bf(sy * inv);
    o[2] = f2bf(sz * inv); o[3] = f2bf(sw * inv);
    *(u16x4*)(xr + s * D_ + c * 4) = o;
  }
}

// ------------- fused transpose + pad fp32 -> bf16 (all 5 weights) -------------
// dst[c][r] = src[r][c]; dst [Cpad][Rpad], zero outside (R,C).
struct TransBatch {
  const float* src[5];
  unsigned short* dst[5];
  int R[5], C[5], Cpad[5], Rpad[5], tiles_c[5], tile0[6];
};

__global__ __launch_bounds__(256)
void transpose_pad_all(TransBatch tb) {
  __shared__ float tile[32][33];
  const int id = blockIdx.x;
  int d = 0;
#pragma unroll
  for (int i = 1; i < 5; ++i) if (id >= tb.tile0[i]) d = i;
  const int lid = id - tb.tile0[d];
  const int tcn = tb.tiles_c[d];
  const int tr = lid / tcn, tc = lid - tr * tcn;
  const float* src = tb.src[d];
  unsigned short* dst = tb.dst[d];
  const int R = tb.R[d], C = tb.C[d], Cpad = tb.Cpad[d], Rpad = tb.Rpad[d];
  const int r0 = tr * 32, c0 = tc * 32;
  const int tx = threadIdx.x & 31, ty = threadIdx.x >> 5;  // 32 x 8
#pragma unroll
  for (int i = 0; i < 32; i += 8) {
    const int r = r0 + ty + i, c = c0 + tx;
    tile[ty + i][tx] = (r < R && c < C) ? src[(size_t)r * C + c] : 0.f;
  }
  __syncthreads();
#pragma unroll
  for (int i = 0; i < 32; i += 8) {
    const int c = c0 + ty + i, r = r0 + tx;
    if (c < Cpad && r < Rpad)
      dst[(size_t)c * Rpad + r] = f2bf(tile[tx][ty + i]);
  }
}

// ---------------- bf16 MFMA GEMM: C[M,N] = A[M,K] @ Bt[N,K]^T ----------------
// BMxBN tile, BK=64, 4 waves (2x2), per-wave (BM/2)x(BN/2) of 16x16x32 frags.
// EPI: 0 = +bias -> fp32 | 1 = +bias,ReLU -> bf16 | 2 = pad-store -> bf16 (col<Nvalid else 0)
//      3 = cross: x*(acc+bias)+x -> bf16 in place (Cb is both input x and output)
template<int EPI, int BM, int BN>
__global__ __launch_bounds__(256)
void mfma_gemm(const unsigned short* __restrict__ A, const unsigned short* __restrict__ Bt,
               const float* __restrict__ bias, float* __restrict__ Cf,
               unsigned short* __restrict__ Cb, int M, int N, int K, int Nvalid)
{
  constexpr int BK = 64;
  constexpr int FM = BM / 32 / 16 * 8;   // = BM/64*... (see below)
  constexpr int WM = BM / 2, WN = BN / 2;          // per-wave tile
  constexpr int NFM = WM / 16, NFN = WN / 16;      // frags per wave
  __shared__ __align__(16) unsigned short As[BM * BK];
  __shared__ __align__(16) unsigned short Bs[BN * BK];
  const int tid  = threadIdx.x;
  const int wave = tid >> 6, lane = tid & 63;
  const int row0 = blockIdx.y * BM;
  const int n0   = blockIdx.x * BN;
  const int wr = (wave >> 1) * WM, wc = (wave & 1) * WN;
  // staging: slot s covers rows 8s..8s+7; lane -> row 8s+(lane>>3), lds chunk lane&7,
  // global chunk pre-swizzled so that LDS[r][cs] holds global chunk cs^(r&7).
  const int srow = lane >> 3;
  const int gc   = (lane & 7) ^ srow;

  f32x4 acc[NFM][NFN];
#pragma unroll
  for (int m = 0; m < NFM; ++m)
#pragma unroll
    for (int n = 0; n < NFN; ++n)
      acc[m][n] = (f32x4){0.f, 0.f, 0.f, 0.f};

  const size_t abase = (size_t)(row0 + srow) * K + (size_t)gc * 8;
  const size_t bbase = (size_t)(n0   + srow) * K + (size_t)gc * 8;

  for (int k0 = 0; k0 < K; k0 += BK) {
#pragma unroll
    for (int i = 0; i < BM / 32; ++i) {
      const int s = wave * (BM / 32) + i;
      gload_lds16(A + abase + (size_t)s * 8 * K + k0, As + s * 512);
    }
#pragma unroll
    for (int i = 0; i < BN / 32; ++i) {
      const int s = wave * (BN / 32) + i;
      gload_lds16(Bt + bbase + (size_t)s * 8 * K + k0, Bs + s * 512);
    }
    __syncthreads();
#pragma unroll
    for (int ks = 0; ks < 2; ++ks) {
      short8 af[NFM], bfr[NFN];
#pragma unroll
      for (int m = 0; m < NFM; ++m) {
        const int r  = wr + m * 16 + (lane & 15);
        const int cs = (ks * 4 + (lane >> 4)) ^ (r & 7);
        af[m] = *(const short8*)(As + r * 64 + cs * 8);
      }
#pragma unroll
      for (int n = 0; n < NFN; ++n) {
        const int r  = wc + n * 16 + (lane & 15);
        const int cs = (ks * 4 + (lane >> 4)) ^ (r & 7);
        bfr[n] = *(const short8*)(Bs + r * 64 + cs * 8);
      }
#pragma unroll
      for (int m = 0; m < NFM; ++m)
#pragma unroll
        for (int n = 0; n < NFN; ++n)
          acc[m][n] = __builtin_amdgcn_mfma_f32_16x16x32_bf16(af[m], bfr[n], acc[m][n], 0, 0, 0);
    }
    __syncthreads();
  }

  const int l15 = lane & 15, l4 = lane >> 4;
#pragma unroll
  for (int m = 0; m < NFM; ++m) {
#pragma unroll
    for (int n = 0; n < NFN; ++n) {
      const int col = n0 + wc + n * 16 + l15;
      const float bv = (EPI == 2) ? 0.f : bias[col];
#pragma unroll
      for (int r = 0; r < 4; ++r) {
        const int row = row0 + wr + m * 16 + l4 * 4 + r;
        const float v = acc[m][n][r];
        if (EPI == 0) {
          Cf[(size_t)row * N + col] = v + bv;
        } else if (EPI == 1) {
          Cb[(size_t)row * N + col] = f2bf(fmaxf(v + bv, 0.f));
        } else if (EPI == 2) {
          Cb[(size_t)row * N + col] = (col < Nvalid) ? f2bf(v) : (unsigned short)0;
        } else {
          const float x = bf2f(Cb[(size_t)row * N + col]);
          Cb[(size_t)row * N + col] = f2bf(fmaf(x, v + bv, x));
        }
      }
    }
  }
}

// ---------------- L2 normalize rows of H [B,128] -> out fp32 ----------------
__global__ __launch_bounds__(256)
void l2norm_kernel(const float* __restrict__ H, float* __restrict__ out) {
  const int w    = threadIdx.x >> 6;
  const int lane = threadIdx.x & 63;
  const int b    = blockIdx.x * 4 + w;
  const float* hr = H + (size_t)b * 128;
  const float v0 = hr[lane];
  const float v1 = hr[lane + 64];
  float s = v0 * v0 + v1 * v1;
#pragma unroll
  for (int off = 32; off; off >>= 1) s += __shfl_xor(s, off);
  const float r = rsqrtf(fmaxf(s, 1e-12f));
  out[(size_t)b * 128 + lane]      = v0 * r;
  out[(size_t)b * 128 + lane + 64] = v1 * r;
}

extern "C" void kernel_launch(void* const* d_in, const int* in_sizes, int n_in,
                              void* d_out, int out_size, void* d_ws, size_t ws_size,
                              hipStream_t stream)
{
  GatherArgs ga;
  for (int s = 0; s < 15; ++s) {
    ga.idx[s] = (const int*)d_in[s];
    ga.tab[s] = (const float*)d_in[15 + s];
  }
  const float* cross_V = (const float*)d_in[30];  // [1920,100]
  const float* cross_U = (const float*)d_in[31];  // [100,1920]
  const float* cross_b = (const float*)d_in[32];  // [1920]
  const float* W0 = (const float*)d_in[33];       // [1920,512]
  const float* b0 = (const float*)d_in[34];
  const float* W1 = (const float*)d_in[35];       // [512,256]
  const float* b1 = (const float*)d_in[36];
  const float* W2 = (const float*)d_in[37];       // [256,128]
  const float* b2 = (const float*)d_in[38];

  char* w = (char*)d_ws;
  unsigned short* Xb  = (unsigned short*)w; w += (size_t)B_ * F_ * 2;    // [8192,1920] bf16
  unsigned short* t   = (unsigned short*)w; w += (size_t)B_ * 128 * 2;   // [8192,128] bf16 (pad 100->128)
  unsigned short* h0  = (unsigned short*)w; w += (size_t)B_ * 512 * 2;   // [8192,512] bf16
  unsigned short* h1  = (unsigned short*)w; w += (size_t)B_ * 256 * 2;   // [8192,256] bf16
  float*          h2  = (float*)w;          w += (size_t)B_ * 128 * 4;   // [8192,128] fp32
  unsigned short* Vt  = (unsigned short*)w; w += (size_t)128 * F_ * 2;   // [128,1920]
  unsigned short* Ut  = (unsigned short*)w; w += (size_t)F_ * 128 * 2;   // [1920,128]
  unsigned short* Wt0 = (unsigned short*)w; w += (size_t)512 * F_ * 2;   // [512,1920]
  unsigned short* Wt1 = (unsigned short*)w; w += (size_t)256 * 512 * 2;  // [256,512]
  unsigned short* Wt2 = (unsigned short*)w; w += (size_t)128 * 256 * 2;  // [128,256]

  const dim3 tb(256);

  // fused weight transposes (fp32 -> bf16, K-major, zero-padded)
  TransBatch tbt;
  const float* srcs[5] = {cross_V, cross_U, W0, W1, W2};
  unsigned short* dsts[5] = {Vt, Ut, Wt0, Wt1, Wt2};
  const int Rs[5]  = {F_, P_, F_, 512, 256};
  const int Cs[5]  = {P_, F_, 512, 256, 128};
  const int Cp[5]  = {128, F_, 512, 256, 128};
  const int Rp[5]  = {F_, 128, F_, 512, 256};
  int acc_t = 0;
  for (int i = 0; i < 5; ++i) {
    tbt.src[i] = srcs[i]; tbt.dst[i] = dsts[i];
    tbt.R[i] = Rs[i]; tbt.C[i] = Cs[i]; tbt.Cpad[i] = Cp[i]; tbt.Rpad[i] = Rp[i];
    tbt.tiles_c[i] = Cp[i] / 32;
    tbt.tile0[i] = acc_t;
    acc_t += (Rp[i] / 32) * (Cp[i] / 32);
  }
  tbt.tile0[5] = acc_t;
  transpose_pad_all<<<acc_t, tb, 0, stream>>>(tbt);

  // 1) gather + pool -> Xb
  gather_pool_kernel<<<B_ / 4, 128, 0, stream>>>(ga, Xb);
  // 2) t = Xb @ V            [8192,128(100 valid)]  grid 2x128=256
  mfma_gemm<2, 64, 64><<<dim3(2, B_ / 64), tb, 0, stream>>>(
      Xb, Vt, nullptr, nullptr, t, B_, 128, F_, P_);
  // 3) Xb = x*(t @ U + b)+x  [8192,1920] in place    grid 15x64=960
  mfma_gemm<3, 128, 128><<<dim3(F_ / 128, B_ / 128), tb, 0, stream>>>(
      t, Ut, cross_b, nullptr, Xb, B_, F_, 128, F_);
  // 4) h0 = relu(Xb @ W0 + b0)   [8192,512]          grid 4x128=512
  mfma_gemm<1, 64, 128><<<dim3(512 / 128, B_ / 64), tb, 0, stream>>>(
      Xb, Wt0, b0, nullptr, h0, B_, 512, F_, 512);
  // 5) h1 = relu(h0 @ W1 + b1)   [8192,256]          grid 4x128=512
  mfma_gemm<1, 64, 64><<<dim3(256 / 64, B_ / 64), tb, 0, stream>>>(
      h0, Wt1, b1, nullptr, h1, B_, 256, 512, 256);
  // 6) h2 = h1 @ W2 + b2         [8192,128] fp32     grid 2x128=256
  mfma_gemm<0, 64, 64><<<dim3(128 / 64, B_ / 64), tb, 0, stream>>>(
      h1, Wt2, b2, h2, nullptr, B_, 128, 256, 128);
  // 7) L2 normalize -> out
  l2norm_kernel<<<B_ / 4, tb, 0, stream>>>(h2, (float*)d_out);
}